// Round 17
// baseline (189.028 us; speedup 1.0000x reference)
//
#include <hip/hip_runtime.h>

// ---------------------------------------------------------------------------
// MNIST Langevin Encoder — round 17: canonical grid-stride copy (G11/m13
// µbench pattern: 2048 persistent blocks x 256 thr, 1 float4/iter) — the one
// copy configuration not yet tried. zero_touched replaces the 4MB zero_win
// (mega reads winner[] only at idx entries). Mega identical to r16 (passed).
// Pipeline: zero_touched -> winner -> prep -> copy -> mega(+scatter)
// ---------------------------------------------------------------------------

#define ZD 64
#define NSTEPS 25
#define EPSI 0.01f
#define K1 784

typedef __attribute__((ext_vector_type(8))) short short8;
typedef __attribute__((ext_vector_type(4))) float f32x4;

__device__ __forceinline__ unsigned short f2bf(float f) {
  union { float f; unsigned u; } v; v.f = f;
  return (unsigned short)((v.u + 0x7FFFu + ((v.u >> 16) & 1u)) >> 16);
}

// ---------------- prep: W1p (frag-major) + Woutp (frag-major) --------------
#define NW1SLOTS 51200
#define NWOSLOTS 8192
__global__ __launch_bounds__(256) void prep_kernel(
    const float* __restrict__ W1, const float* __restrict__ W21,
    const float* __restrict__ W22, short* __restrict__ W1p,
    short* __restrict__ Woutp) {
  const int t = blockIdx.x * 256 + threadIdx.x;
  if (t < NW1SLOTS) {
    const int g = t / 1600;
    const int rem = t - g * 1600;
    const int kc32 = rem >> 6;
    const int l = rem & 63;
    const int col = g * 16 + (l & 15);
    const int k = kc32 * 32 + (l >> 4) * 8;
    short8 v = {0, 0, 0, 0, 0, 0, 0, 0};
    if (col < 400 && k + 8 <= K1) {
      const float* s = W1 + (long)col * K1 + k;
#pragma unroll
      for (int e = 0; e < 8; e++) v[e] = (short)f2bf(s[e]);
    }
    *(short8*)(W1p + (long)t * 8) = v;
  } else {
    const int u = t - NW1SLOTS;
    if (u < NWOSLOTS) {
      const int g = u >> 10;
      const int rem = u & 1023;
      const int kc32 = rem >> 6;
      const int l = u & 63;
      const int row = g * 16 + (l & 15);
      const int k = kc32 * 32 + (l >> 4) * 8;
      short8 v = {0, 0, 0, 0, 0, 0, 0, 0};
      if (k + 8 <= 400) {
        const float* s = (row < 64) ? (W21 + (long)row * 400 + k)
                                    : (W22 + (long)(row - 64) * 400 + k);
#pragma unroll
        for (int e = 0; e < 8; e++) v[e] = (short)f2bf(s[e]);
      }
      *(short8*)(Woutp + (long)u * 8) = v;
    }
  }
}

// ---------------- zero only the winner entries we will read ----------------
__global__ __launch_bounds__(256) void zero_touched_kernel(
    const int* __restrict__ idx, int* __restrict__ winner, int B) {
  const int j = blockIdx.x * 256 + threadIdx.x;
  if (j < B) winner[idx[j]] = 0;     // races benign: all write 0
}

// ---------------- winner: last duplicate index wins ------------------------
__global__ __launch_bounds__(256) void winner_kernel(
    const int* __restrict__ idx, int* __restrict__ winner, int B) {
  const int j = blockIdx.x * 256 + threadIdx.x;
  if (j < B) atomicMax(&winner[idx[j]], j + 1);
}

// ---------------- canonical grid-stride copy (G11 / m13 pattern) -----------
#define COPY_GRID 2048
__global__ __launch_bounds__(256) void copy_kernel(
    const f32x4* __restrict__ src, f32x4* __restrict__ dst, long n4) {
  const long stride = (long)COPY_GRID * 256;
  for (long e = (long)blockIdx.x * 256 + threadIdx.x; e < n4; e += stride) {
    dst[e] = src[e];
  }
}

// ---------------- MEGA (BM=32, 4 waves, 50KB LDS, 3 blocks/CU) — r16 -------
__global__ __launch_bounds__(256, 3) void mega_kernel(
    const float* __restrict__ X, const short* __restrict__ W1p,
    const short* __restrict__ Woutp, const float* __restrict__ b1,
    const float* __restrict__ b21, const float* __restrict__ b22,
    const float* __restrict__ cache, const int* __restrict__ idx,
    const float* __restrict__ noise, const int* __restrict__ winner,
    float* __restrict__ out_logq, float* __restrict__ out_z,
    float* __restrict__ out_cache, int B) {
  __shared__ char smem[51200];
  const int tid = threadIdx.x;
  const int w = tid >> 6;
  const int lane = tid & 63;
  const int m0 = blockIdx.x * 32;

  // ---- phase 1: stage x-tile (32x800 bf16, frag-major) ----
  {
    short* As = (short*)smem;
    for (int slot = tid; slot < 3200; slot += 256) {
      const int lp = slot & 63;
      const int chunk = slot >> 6;       // kc32*2 + rg
      const int rg = chunk & 1;
      const int kc32 = chunk >> 1;
      const int row = rg * 16 + (lp & 15);
      const int k = kc32 * 32 + (lp >> 4) * 8;
      short8 av = {0, 0, 0, 0, 0, 0, 0, 0};
      if (k + 8 <= K1) {
        const float4 f0 = *(const float4*)(X + (long)(m0 + row) * K1 + k);
        const float4 f1 = *(const float4*)(X + (long)(m0 + row) * K1 + k + 4);
        av[0] = (short)f2bf(f0.x); av[1] = (short)f2bf(f0.y);
        av[2] = (short)f2bf(f0.z); av[3] = (short)f2bf(f0.w);
        av[4] = (short)f2bf(f1.x); av[5] = (short)f2bf(f1.y);
        av[6] = (short)f2bf(f1.z); av[7] = (short)f2bf(f1.w);
      }
      *(short8*)(As + (long)slot * 8) = av;
    }
  }
  __syncthreads();

  // ---- phase 2: gemm1 K-loop (barrier-free) ----
  const f32x4 vzero = {0.f, 0.f, 0.f, 0.f};
  f32x4 acc[2][8];
#pragma unroll
  for (int i = 0; i < 2; i++)
#pragma unroll
    for (int j = 0; j < 8; j++) acc[i][j] = vzero;
  {
    const short8* Ap = (const short8*)smem;
    const short8* Bp = (const short8*)W1p;
    for (int kc = 0; kc < 25; kc++) {
      short8 a[2], b[8];
#pragma unroll
      for (int rg = 0; rg < 2; rg++) a[rg] = Ap[(kc * 2 + rg) * 64 + lane];
#pragma unroll
      for (int j = 0; j < 8; j++) b[j] = Bp[((w * 8 + j) * 25 + kc) * 64 + lane];
#pragma unroll
      for (int rg = 0; rg < 2; rg++)
#pragma unroll
        for (int j = 0; j < 8; j++)
          acc[rg][j] = __builtin_amdgcn_mfma_f32_16x16x32_bf16(a[rg], b[j], acc[rg][j], 0, 0, 0);
    }
  }
  __syncthreads();

  // ---- phase 3: h (bias+relu, bf16) -> LDS frag-major ----
  {
    unsigned short* hl = (unsigned short*)smem;
#pragma unroll
    for (int j = 0; j < 8; j++) {
      const int col = w * 128 + j * 16 + (lane & 15);
      const float bias = (col < 400) ? b1[col] : 0.f;
#pragma unroll
      for (int rg = 0; rg < 2; rg++) {
#pragma unroll
        for (int r = 0; r < 4; r++) {
          const int row = rg * 16 + (lane >> 4) * 4 + r;
          const float v = fmaxf(acc[rg][j][r] + bias, 0.f);
          const int sidx = (((col >> 5) * 2 + (row >> 4)) * 64 + (row & 15) +
                            (((col >> 3) & 3) << 4)) * 8 + (col & 7);
          hl[sidx] = f2bf(v);
        }
      }
    }
  }
  __syncthreads();

  // ---- phase 4: gemm2 (32x128 = h @ Wout^T), K=512 from LDS-h ----
  f32x4 acc2[4];
#pragma unroll
  for (int j = 0; j < 4; j++) acc2[j] = vzero;
  {
    const short8* Hp = (const short8*)smem;
    const short8* Bp = (const short8*)Woutp;
    const int rg2 = w >> 1;
    const int gbase = (w & 1) * 4;
    for (int kc32 = 0; kc32 < 16; kc32++) {
      const short8 a = Hp[(kc32 * 2 + rg2) * 64 + lane];
#pragma unroll
      for (int j = 0; j < 4; j++) {
        const short8 b = Bp[((gbase + j) * 16 + kc32) * 64 + lane];
        acc2[j] = __builtin_amdgcn_mfma_f32_16x16x32_bf16(a, b, acc2[j], 0, 0, 0);
      }
    }
  }

  // ---- phase 5: zloc/u -> LDS (disjoint region [32,48KB)) ----
  {
    float* zl = (float*)(smem + 32768);
    float* ul = (float*)(smem + 40960);
    const int rg2 = w >> 1;
    const bool is_u = (w & 1);
    const float* bp = is_u ? b22 : b21;
    float* outp = is_u ? ul : zl;
#pragma unroll
    for (int j = 0; j < 4; j++) {
      const int col = j * 16 + (lane & 15);
      const float bias = bp[col];
#pragma unroll
      for (int r = 0; r < 4; r++) {
        const int row = rg2 * 16 + (lane >> 4) * 4 + r;
        outp[row * 64 + col] = acc2[j][r] + bias;
      }
    }
  }
  __syncthreads();

  // ---- phase 6: langevin + logq + winner scatter ----
  {
    const float* zl = (const float*)(smem + 32768);
    const float* ul = (const float*)(smem + 40960);
    const float coef = sqrtf(2.f * EPSI);
    const long strideN = (long)B * ZD;
    for (int q = 0; q < 8; q++) {
      const int lr = w * 8 + q;
      const int gr = m0 + lr;
      const int i = idx[gr];
      const float zloc = zl[lr * 64 + lane];
      const float uu = ul[lr * 64 + lane];
      const float a = EPSI * expf(-2.f * uu);
      float z = cache[(long)i * ZD + lane];
      const float* np = noise + (long)gr * ZD + lane;
#pragma unroll
      for (int s = 0; s < NSTEPS; s++) {
        z = z + a * (zloc - z) + coef * np[(long)s * strideN];
      }
      out_z[(long)gr * ZD + lane] = z;
      if (winner[i] == gr + 1) {
        out_cache[(long)i * ZD + lane] = z;
      }
      const float d = (z - zloc) * expf(-uu);
      float t = -0.5f * d * d - uu - 0.91893853320467274178f;
#pragma unroll
      for (int off = 1; off < 64; off <<= 1) t += __shfl_xor(t, off);
      if (lane == 0) out_logq[gr] = t;
    }
  }
}

extern "C" void kernel_launch(void* const* d_in, const int* in_sizes, int n_in,
                              void* d_out, int out_size, void* d_ws, size_t ws_size,
                              hipStream_t stream) {
  const float* x     = (const float*)d_in[0];
  const int*   idx   = (const int*)d_in[1];
  const float* W1    = (const float*)d_in[3];
  const float* b1    = (const float*)d_in[4];
  const float* W21   = (const float*)d_in[5];
  const float* b21   = (const float*)d_in[6];
  const float* W22   = (const float*)d_in[7];
  const float* b22   = (const float*)d_in[8];
  const float* cache = (const float*)d_in[9];
  const float* noise = (const float*)d_in[10];

  const int B  = in_sizes[1];            // 16384
  const int DS = in_sizes[9] / ZD;       // 1000000

  float* out_logq  = (float*)d_out;
  float* out_z     = out_logq + B;
  float* out_cache = out_z + (long)B * ZD;

  // workspace: W1p 800KB + Woutp 128KB + win 4MB  (~5MB)
  short* w1p   = (short*)d_ws;
  short* woutp = w1p + (long)NW1SLOTS * 8;
  int*   win   = (int*)(woutp + (long)NWOSLOTS * 8);

  zero_touched_kernel<<<(B + 255) / 256, 256, 0, stream>>>(idx, win, B);
  winner_kernel<<<(B + 255) / 256, 256, 0, stream>>>(idx, win, B);

  const int prep_slots = NW1SLOTS + NWOSLOTS;
  prep_kernel<<<(prep_slots + 255) / 256, 256, 0, stream>>>(W1, W21, W22, w1p, woutp);

  const long n4 = (long)DS * (ZD / 4);   // 16,000,000 float4
  copy_kernel<<<COPY_GRID, 256, 0, stream>>>(
      (const f32x4*)cache, (f32x4*)out_cache, n4);

  mega_kernel<<<B / 32, 256, 0, stream>>>(
      x, w1p, woutp, b1, b21, b22, cache, idx, noise, win,
      out_logq, out_z, out_cache, B);
}

// Round 18
// 174.812 us; speedup vs baseline: 1.0813x; 1.0813x over previous
//
#include <hip/hip_runtime.h>

// ---------------------------------------------------------------------------
// MNIST Langevin Encoder — round 18: revert to r13 (best measured: 175.8us).
// Copy-pattern space is exhausted (8 variants incl. vendor blit, all ~4.3
// TB/s for the 512MB mixed stream); overlap proven non-additive (r8/r12/r15).
// Pipeline: zero_win -> prep -> winner -> copy -> mega(+scatter)
// ---------------------------------------------------------------------------

#define ZD 64
#define NSTEPS 25
#define EPSI 0.01f
#define K1 784
#define HSTR 512

typedef __attribute__((ext_vector_type(8))) short short8;
typedef __attribute__((ext_vector_type(4))) float f32x4;
typedef __attribute__((ext_vector_type(4))) int i32x4;

__device__ __forceinline__ unsigned short f2bf(float f) {
  union { float f; unsigned u; } v; v.f = f;
  return (unsigned short)((v.u + 0x7FFFu + ((v.u >> 16) & 1u)) >> 16);
}

// ---------------- prep: W1p (frag-major) + Woutp (frag-major) --------------
// W1p slot = (g*25 + kc32)*64 + l  : W1[g*16+(l&15)][kc32*32+(l>>4)*8..+8]
// Woutp slot = (g*16 + kc32)*64 + l: Wrow[g*16+(l&15)][kc32*32+(l>>4)*8..+8]
//   where Wrow n = W21 row n (n<64) else W22 row n-64; K=400 padded to 512.
#define NW1SLOTS 51200
#define NWOSLOTS 8192
__global__ __launch_bounds__(256) void prep_kernel(
    const float* __restrict__ W1, const float* __restrict__ W21,
    const float* __restrict__ W22, short* __restrict__ W1p,
    short* __restrict__ Woutp) {
  const int t = blockIdx.x * 256 + threadIdx.x;
  if (t < NW1SLOTS) {
    const int g = t / 1600;
    const int rem = t - g * 1600;
    const int kc32 = rem >> 6;
    const int l = rem & 63;
    const int col = g * 16 + (l & 15);
    const int k = kc32 * 32 + (l >> 4) * 8;
    short8 v = {0, 0, 0, 0, 0, 0, 0, 0};
    if (col < 400 && k + 8 <= K1) {
      const float* s = W1 + (long)col * K1 + k;
#pragma unroll
      for (int e = 0; e < 8; e++) v[e] = (short)f2bf(s[e]);
    }
    *(short8*)(W1p + (long)t * 8) = v;
  } else {
    const int u = t - NW1SLOTS;
    if (u < NWOSLOTS) {
      const int g = u >> 10;            // u / 1024
      const int rem = u & 1023;
      const int kc32 = rem >> 6;
      const int l = u & 63;
      const int row = g * 16 + (l & 15);    // 0..127
      const int k = kc32 * 32 + (l >> 4) * 8;
      short8 v = {0, 0, 0, 0, 0, 0, 0, 0};
      if (k + 8 <= 400) {
        const float* s = (row < 64) ? (W21 + (long)row * 400 + k)
                                    : (W22 + (long)(row - 64) * 400 + k);
#pragma unroll
        for (int e = 0; e < 8; e++) v[e] = (short)f2bf(s[e]);
      }
      *(short8*)(Woutp + (long)u * 8) = v;
    }
  }
}

// ---------------- zero winner array ----------------------------------------
__global__ __launch_bounds__(256) void zero_win_kernel(i32x4* __restrict__ win4, int n4i) {
  const int t = blockIdx.x * 256 + threadIdx.x;
  if (t < n4i) win4[t] = (i32x4){0, 0, 0, 0};
}

// ---------------- winner: last duplicate index wins ------------------------
__global__ __launch_bounds__(256) void winner_kernel(
    const int* __restrict__ idx, int* __restrict__ winner, int B) {
  const int j = blockIdx.x * 256 + threadIdx.x;
  if (j < B) atomicMax(&winner[idx[j]], j + 1);
}

// ---------------- stream copy (r11, proven): 4 float4/thread ---------------
__global__ __launch_bounds__(256) void copy_kernel(
    const f32x4* __restrict__ src, f32x4* __restrict__ dst) {
  const long base = (long)blockIdx.x * 1024 + threadIdx.x;
  f32x4 v0 = src[base];
  f32x4 v1 = src[base + 256];
  f32x4 v2 = src[base + 512];
  f32x4 v3 = src[base + 768];
  dst[base] = v0;
  dst[base + 256] = v1;
  dst[base + 512] = v2;
  dst[base + 768] = v3;
}

// ---------------- MEGA: gemm1 -> gemm2 -> langevin, block = 64 rows --------
// LDS: [0,100KB) stage-A (6400 short8); after gemm1 reused as:
//   [0,64KB)  h frag-major (4096 short8)
//   [64KB,80KB) zloc f32 [64][64]
//   [80KB,96KB) u    f32 [64][64]
__global__ __launch_bounds__(512, 2) void mega_kernel(
    const float* __restrict__ X, const short* __restrict__ W1p,
    const short* __restrict__ Woutp, const float* __restrict__ b1,
    const float* __restrict__ b21, const float* __restrict__ b22,
    const float* __restrict__ cache, const int* __restrict__ idx,
    const float* __restrict__ noise, const int* __restrict__ winner,
    float* __restrict__ out_logq, float* __restrict__ out_z,
    float* __restrict__ out_cache, int B) {
  __shared__ char smem[102400];
  const int tid = threadIdx.x;
  const int w = tid >> 6;
  const int lane = tid & 63;
  const int m0 = blockIdx.x * 64;

  // ---- phase 1: stage x-tile (64x800 bf16, frag-major) ----
  {
    short* As = (short*)smem;
    for (int slot = tid; slot < 6400; slot += 512) {
      const int lp = slot & 63;
      const int chunk = slot >> 6;       // kc32*4 + rg
      const int rg = chunk & 3;
      const int kc32 = chunk >> 2;
      const int row = rg * 16 + (lp & 15);
      const int k = kc32 * 32 + (lp >> 4) * 8;
      short8 av = {0, 0, 0, 0, 0, 0, 0, 0};
      if (k + 8 <= K1) {
        const float4 f0 = *(const float4*)(X + (long)(m0 + row) * K1 + k);
        const float4 f1 = *(const float4*)(X + (long)(m0 + row) * K1 + k + 4);
        av[0] = (short)f2bf(f0.x); av[1] = (short)f2bf(f0.y);
        av[2] = (short)f2bf(f0.z); av[3] = (short)f2bf(f0.w);
        av[4] = (short)f2bf(f1.x); av[5] = (short)f2bf(f1.y);
        av[6] = (short)f2bf(f1.z); av[7] = (short)f2bf(f1.w);
      }
      *(short8*)(As + (long)slot * 8) = av;
    }
  }
  __syncthreads();

  // ---- phase 2: gemm1 K-loop (barrier-free) ----
  const f32x4 vzero = {0.f, 0.f, 0.f, 0.f};
  f32x4 acc[4][4];
#pragma unroll
  for (int i = 0; i < 4; i++)
#pragma unroll
    for (int j = 0; j < 4; j++) acc[i][j] = vzero;
  {
    const short8* Ap = (const short8*)smem;
    const short8* Bp = (const short8*)W1p;
    for (int kc = 0; kc < 25; kc++) {
      short8 a[4], b[4];
#pragma unroll
      for (int rg = 0; rg < 4; rg++) a[rg] = Ap[(kc * 4 + rg) * 64 + lane];
#pragma unroll
      for (int j = 0; j < 4; j++) b[j] = Bp[((w * 4 + j) * 25 + kc) * 64 + lane];
#pragma unroll
      for (int rg = 0; rg < 4; rg++)
#pragma unroll
        for (int j = 0; j < 4; j++)
          acc[rg][j] = __builtin_amdgcn_mfma_f32_16x16x32_bf16(a[rg], b[j], acc[rg][j], 0, 0, 0);
    }
  }
  __syncthreads();   // all waves done reading stage-A

  // ---- phase 3: h (bias+relu, bf16) -> LDS frag-major ----
  {
    unsigned short* hl = (unsigned short*)smem;
#pragma unroll
    for (int j = 0; j < 4; j++) {
      const int col = w * 64 + j * 16 + (lane & 15);
      const float bias = (col < 400) ? b1[col] : 0.f;
#pragma unroll
      for (int rg = 0; rg < 4; rg++) {
#pragma unroll
        for (int r = 0; r < 4; r++) {
          const int row = rg * 16 + (lane >> 4) * 4 + r;
          const float v = fmaxf(acc[rg][j][r] + bias, 0.f);
          const int sidx = (((col >> 5) * 4 + (row >> 4)) * 64 + (row & 15) +
                            (((col >> 3) & 3) << 4)) * 8 + (col & 7);
          hl[sidx] = f2bf(v);
        }
      }
    }
  }
  __syncthreads();

  // ---- phase 4: gemm2 (64x128 = h @ Wout^T), K=512 from LDS-h ----
  f32x4 acc2[4];
#pragma unroll
  for (int j = 0; j < 4; j++) acc2[j] = vzero;
  {
    const short8* Hp = (const short8*)smem;
    const short8* Bp = (const short8*)Woutp;
    const int rg2 = w >> 1;
    const int gbase = (w & 1) * 4;
    for (int kc32 = 0; kc32 < 16; kc32++) {
      const short8 a = Hp[(kc32 * 4 + rg2) * 64 + lane];
#pragma unroll
      for (int j = 0; j < 4; j++) {
        const short8 b = Bp[((gbase + j) * 16 + kc32) * 64 + lane];
        acc2[j] = __builtin_amdgcn_mfma_f32_16x16x32_bf16(a, b, acc2[j], 0, 0, 0);
      }
    }
  }

  // ---- phase 5: zloc/u -> LDS (disjoint region; no barrier needed) ----
  {
    float* zl = (float*)(smem + 65536);
    float* ul = (float*)(smem + 81920);
    const int rg2 = w >> 1;
    const bool is_u = (w & 1);
    const float* bp = is_u ? b22 : b21;
    float* outp = is_u ? ul : zl;
#pragma unroll
    for (int j = 0; j < 4; j++) {
      const int col = j * 16 + (lane & 15);
      const float bias = bp[col];
#pragma unroll
      for (int r = 0; r < 4; r++) {
        const int row = rg2 * 16 + (lane >> 4) * 4 + r;
        outp[row * 64 + col] = acc2[j][r] + bias;
      }
    }
  }
  __syncthreads();

  // ---- phase 6: langevin + logq + winner scatter ----
  {
    const float* zl = (const float*)(smem + 65536);
    const float* ul = (const float*)(smem + 81920);
    const float coef = sqrtf(2.f * EPSI);
    const long strideN = (long)B * ZD;
    for (int q = 0; q < 8; q++) {
      const int lr = w * 8 + q;
      const int gr = m0 + lr;
      const int i = idx[gr];
      const float zloc = zl[lr * 64 + lane];
      const float uu = ul[lr * 64 + lane];
      const float a = EPSI * expf(-2.f * uu);
      float z = cache[(long)i * ZD + lane];
      const float* np = noise + (long)gr * ZD + lane;
#pragma unroll
      for (int s = 0; s < NSTEPS; s++) {
        z = z + a * (zloc - z) + coef * np[(long)s * strideN];
      }
      out_z[(long)gr * ZD + lane] = z;
      if (winner[i] == gr + 1) {
        out_cache[(long)i * ZD + lane] = z;
      }
      const float d = (z - zloc) * expf(-uu);
      float t = -0.5f * d * d - uu - 0.91893853320467274178f;
#pragma unroll
      for (int off = 1; off < 64; off <<= 1) t += __shfl_xor(t, off);
      if (lane == 0) out_logq[gr] = t;
    }
  }
}

extern "C" void kernel_launch(void* const* d_in, const int* in_sizes, int n_in,
                              void* d_out, int out_size, void* d_ws, size_t ws_size,
                              hipStream_t stream) {
  const float* x     = (const float*)d_in[0];
  const int*   idx   = (const int*)d_in[1];
  const float* W1    = (const float*)d_in[3];
  const float* b1    = (const float*)d_in[4];
  const float* W21   = (const float*)d_in[5];
  const float* b21   = (const float*)d_in[6];
  const float* W22   = (const float*)d_in[7];
  const float* b22   = (const float*)d_in[8];
  const float* cache = (const float*)d_in[9];
  const float* noise = (const float*)d_in[10];

  const int B  = in_sizes[1];            // 16384
  const int DS = in_sizes[9] / ZD;       // 1000000

  float* out_logq  = (float*)d_out;
  float* out_z     = out_logq + B;
  float* out_cache = out_z + (long)B * ZD;

  // workspace: W1p 800KB + Woutp 128KB + win 4MB  (~5MB)
  short* w1p   = (short*)d_ws;                        // 51200*8 bf16
  short* woutp = w1p + (long)NW1SLOTS * 8;            // 8192*8 bf16
  int*   win   = (int*)(woutp + (long)NWOSLOTS * 8);  // DS ints

  const int n4i = (DS + 3) / 4;
  zero_win_kernel<<<(n4i + 255) / 256, 256, 0, stream>>>((i32x4*)win, n4i);

  const int prep_slots = NW1SLOTS + NWOSLOTS;         // 59392
  prep_kernel<<<(prep_slots + 255) / 256, 256, 0, stream>>>(W1, W21, W22, w1p, woutp);
  winner_kernel<<<(B + 255) / 256, 256, 0, stream>>>(idx, win, B);

  const long n4 = (long)DS * (ZD / 4);                // 16,000,000 float4
  copy_kernel<<<(unsigned)(n4 / 1024), 256, 0, stream>>>(
      (const f32x4*)cache, (f32x4*)out_cache);

  mega_kernel<<<B / 64, 512, 0, stream>>>(
      x, w1p, woutp, b1, b21, b22, cache, idx, noise, win,
      out_logq, out_z, out_cache, B);
}